// Round 6
// baseline (863.802 us; speedup 1.0000x reference)
//
#include <hip/hip_runtime.h>
#include <math.h>

#define TT 35
#define DD 10
#define HD 400
#define WD 352
#define CIN 7
#define U1 16
#define U2 32
#define EPSV 1e-5f

// ws float layout
#define WS_SUM1 256   // 32 copies x 16
#define WS_SSQ1 768
#define WS_SUM2 1280  // 16 copies x 32
#define WS_SSQ2 1792
#define NC1 32
#define NC2 16
#define WS_ZERO_FLOATS 2304
#define WS_SUM_OFF 4096  // per-voxel channel summaries start here

typedef __bf16 bf16x8 __attribute__((ext_vector_type(8)));
typedef float f32x4 __attribute__((ext_vector_type(4)));

__device__ inline unsigned short f2bf(float x) {
  unsigned u = __builtin_bit_cast(unsigned, x);
  unsigned r = (u + 0x7fff + ((u >> 16) & 1)) >> 16;
  return (unsigned short)r;
}

// ---------------------------------------------------------------------------
// Layer-1 BN statistics + first 58% of the output zero-fill.
// Stats part is latency-bound (39MB read); its write pipe is idle, so the
// fill rides along here and overlaps with the vfe pipeline position.
// ---------------------------------------------------------------------------
__global__ __launch_bounds__(256) void k_stats1(
    const float* __restrict__ feat, const float* __restrict__ w1,
    const float* __restrict__ b1, float* __restrict__ ws, int P,
    float4* __restrict__ out4, long fill_hi) {
  __shared__ float s_w1[CIN * U1];
  __shared__ float s_b1[U1];
  __shared__ float s_red[4][2 * U1];

  int tid = threadIdx.x;
  if (tid < CIN * U1) s_w1[tid] = w1[tid];
  if (tid < U1) s_b1[tid] = b1[tid];
  __syncthreads();

  float sum[U1], ssq[U1];
#pragma unroll
  for (int u = 0; u < U1; ++u) { sum[u] = 0.f; ssq[u] = 0.f; }

  int stride = gridDim.x * blockDim.x;
  for (int p = blockIdx.x * blockDim.x + tid; p < P; p += stride) {
    const float* f = feat + (size_t)p * CIN;
    float x[CIN];
#pragma unroll
    for (int c = 0; c < CIN; ++c) x[c] = f[c];
#pragma unroll
    for (int u = 0; u < U1; ++u) {
      float acc = s_b1[u];
#pragma unroll
      for (int c = 0; c < CIN; ++c) acc += x[c] * s_w1[c * U1 + u];
      float h = fmaxf(acc, 0.f);
      sum[u] += h;
      ssq[u] += h * h;
    }
  }

  int lane = tid & 63, wv = tid >> 6;
#pragma unroll
  for (int u = 0; u < U1; ++u) {
    float s = sum[u], q = ssq[u];
    for (int off = 32; off; off >>= 1) {
      s += __shfl_down(s, off);
      q += __shfl_down(q, off);
    }
    if (lane == 0) { s_red[wv][u] = s; s_red[wv][U1 + u] = q; }
  }
  __syncthreads();
  if (tid < 2 * U1) {
    float tot = s_red[0][tid] + s_red[1][tid] + s_red[2][tid] + s_red[3][tid];
    int copy = blockIdx.x & (NC1 - 1);
    int u = tid & (U1 - 1);
    int base = (tid < U1) ? WS_SUM1 : WS_SSQ1;
    atomicAdd(&ws[base + copy * U1 + u], tot);
  }

  // ---- fill epilogue: out4[0 .. fill_hi) ----
  long gtid = (long)blockIdx.x * 256 + tid;
  long gstride = (long)gridDim.x * 256;
  float4 zz = make_float4(0.f, 0.f, 0.f, 0.f);
  for (long i = gtid; i < fill_hi; i += gstride) out4[i] = zz;
}

// ---------------------------------------------------------------------------
// Main pass: one wave per voxel, 4 voxels/block.
//  - per-wave fin1; stage1 in registers; cat -> bf16 LDS; 6x MFMA
//  - per-(voxel,channel) summaries {maxm,minm,maxa,mina} (fp32) + cnt
//  - layer-2 stats partials -> ws atomics
//  - epilogue: zero-fill of out4[fill_lo .. n4)
// ---------------------------------------------------------------------------
__global__ __launch_bounds__(256) void k_vfe2(
    const float* __restrict__ feat, const float* __restrict__ w1,
    const float* __restrict__ b1, const float* __restrict__ g1,
    const float* __restrict__ be1, const float* __restrict__ w2,
    const float* __restrict__ b2, float* __restrict__ ws,
    float* __restrict__ sumg, float* __restrict__ cntg,
    float4* __restrict__ out4, long fill_lo, long n4, int K, float invN) {
  __shared__ unsigned short s_w2b[32 * 40];     // [n][c'] stride 40
  __shared__ unsigned short s_catb[4][48][32];  // bf16 cat; pad rows 35-47 = 0
  __shared__ float s_mk[4][40];                 // mask per row
  __shared__ float s_red[4][64];

  int tid = threadIdx.x;
  int lane = tid & 63, wv = tid >> 6;
  int g = lane >> 4, u = lane & 15;
  int v = blockIdx.x * 4 + wv;
  bool active = (v < K);

  // ---- stage w2 -> bf16, transposed + K-permuted (c'=2i<->c=i, c'=2i+1<->c=16+i)
  for (int i = tid; i < 32 * 32; i += 256) {
    int n = i >> 5, cp = i & 31;
    int c = (cp & 1) ? (16 + (cp >> 1)) : (cp >> 1);
    s_w2b[n * 40 + cp] = f2bf(w2[c * 32 + n]);
  }
  // ---- zero M-pad rows 35..47 of each wave's cat tile ----
  {
    unsigned* z = (unsigned*)s_catb;
    for (int i = tid; i < 4 * 13 * 16; i += 256) {
      int w = i / 208, rem = i % 208;
      int row = 35 + (rem >> 4), k = rem & 15;
      z[(w * 48 + row) * 16 + k] = 0u;
    }
  }

  // ---- per-lane fin1: BN1 affine for channel u ----
  float s1 = 0.f, q1 = 0.f;
#pragma unroll
  for (int c = 0; c < NC1; ++c) {
    s1 += ws[WS_SUM1 + c * U1 + u];
    q1 += ws[WS_SSQ1 + c * U1 + u];
  }
  float mean1 = s1 * invN;
  float var1 = q1 * invN - mean1 * mean1;
  float A1 = g1[u] / sqrtf(var1 + EPSV);
  float B1 = be1[u] - mean1 * A1;

  float w1r[CIN];
#pragma unroll
  for (int c = 0; c < CIN; ++c) w1r[c] = w1[c * U1 + u];
  float b1u = b1[u];

  // ---- stage 1: rows t = g + 4j ----
  float h1n[9], mkv[9];
  float aggl = -INFINITY;
  float cntl = 0.f;
  const float* fv = feat + (size_t)v * (TT * CIN);
#pragma unroll
  for (int j = 0; j < 9; ++j) {
    int t = g + 4 * j;
    h1n[j] = -INFINITY;
    mkv[j] = 0.f;
    if (active && t < TT) {
      const float* fr = fv + t * CIN;
      float x0 = fr[0], x1 = fr[1], x2 = fr[2], x3 = fr[3];
      float x4 = fr[4], x5 = fr[5], x6 = fr[6];
      float m = fmaxf(fmaxf(fmaxf(x0, x1), fmaxf(x2, x3)),
                      fmaxf(fmaxf(x4, x5), x6));
      float mk = (m != 0.f) ? 1.f : 0.f;
      float acc = b1u + x0 * w1r[0] + x1 * w1r[1] + x2 * w1r[2] +
                  x3 * w1r[3] + x4 * w1r[4] + x5 * w1r[5] + x6 * w1r[6];
      float h = fmaxf(acc, 0.f);
      h1n[j] = A1 * h + B1;
      mkv[j] = mk;
      cntl += mk;
      if (u == 0) s_mk[wv][t] = mk;
      aggl = fmaxf(aggl, h1n[j]);
    }
  }
  // agg1 / cnt across the 4 g-groups (u-lanes within a group are identical)
  aggl = fmaxf(aggl, __shfl_xor(aggl, 16));
  aggl = fmaxf(aggl, __shfl_xor(aggl, 32));
  cntl += __shfl_xor(cntl, 16);
  cntl += __shfl_xor(cntl, 32);
  if (active && lane == 0) cntg[v] = cntl;

  // ---- write cat rows: packed (h*mk, agg*mk) bf16x2 at cols (2u, 2u+1) ----
#pragma unroll
  for (int j = 0; j < 9; ++j) {
    int t = g + 4 * j;
    if (active && t < TT) {
      unsigned pk = (unsigned)f2bf(h1n[j] * mkv[j]) |
                    ((unsigned)f2bf(aggl * mkv[j]) << 16);
      *(unsigned*)&s_catb[wv][t][2 * u] = pk;
    }
  }
  __syncthreads();

  // ---- stage 2: 6x MFMA ----
  f32x4 acc[2][3];
#pragma unroll
  for (int nt = 0; nt < 2; ++nt)
#pragma unroll
    for (int mt = 0; mt < 3; ++mt) acc[nt][mt] = (f32x4)(0.f);

  bf16x8 bfr[2];
#pragma unroll
  for (int nt = 0; nt < 2; ++nt) {
    uint4 raw = *(const uint4*)&s_w2b[(nt * 16 + u) * 40 + g * 8];
    bfr[nt] = __builtin_bit_cast(bf16x8, raw);
  }
#pragma unroll
  for (int mt = 0; mt < 3; ++mt) {
    uint4 raw = *(const uint4*)&s_catb[wv][mt * 16 + u][g * 8];
    bf16x8 afr = __builtin_bit_cast(bf16x8, raw);
#pragma unroll
    for (int nt = 0; nt < 2; ++nt)
      acc[nt][mt] =
          __builtin_amdgcn_mfma_f32_16x16x32_bf16(afr, bfr[nt], acc[nt][mt], 0, 0, 0);
  }

  // ---- bias+relu, layer-2 stats, channel summaries ----
  float b2c[2] = {b2[u], b2[16 + u]};
  float sum[2] = {0.f, 0.f}, ssq[2] = {0.f, 0.f};
  float maxm[2] = {-INFINITY, -INFINITY}, minm[2] = {INFINITY, INFINITY};
  float maxa[2] = {-INFINITY, -INFINITY}, mina[2] = {INFINITY, INFINITY};
#pragma unroll
  for (int nt = 0; nt < 2; ++nt) {
#pragma unroll
    for (int mt = 0; mt < 3; ++mt) {
#pragma unroll
      for (int r = 0; r < 4; ++r) {
        int row = mt * 16 + g * 4 + r;
        if (row < TT) {
          float h = fmaxf(acc[nt][mt][r] + b2c[nt], 0.f);
          sum[nt] += h;
          ssq[nt] += h * h;
          maxa[nt] = fmaxf(maxa[nt], h);
          mina[nt] = fminf(mina[nt], h);
          float mk = s_mk[wv][row];
          if (mk != 0.f) {
            maxm[nt] = fmaxf(maxm[nt], h);
            minm[nt] = fminf(minm[nt], h);
          }
        }
      }
    }
  }

  // reduce all summaries + stats across g-groups
#pragma unroll
  for (int nt = 0; nt < 2; ++nt) {
    sum[nt] += __shfl_xor(sum[nt], 16);
    sum[nt] += __shfl_xor(sum[nt], 32);
    ssq[nt] += __shfl_xor(ssq[nt], 16);
    ssq[nt] += __shfl_xor(ssq[nt], 32);
    maxa[nt] = fmaxf(maxa[nt], __shfl_xor(maxa[nt], 16));
    maxa[nt] = fmaxf(maxa[nt], __shfl_xor(maxa[nt], 32));
    mina[nt] = fminf(mina[nt], __shfl_xor(mina[nt], 16));
    mina[nt] = fminf(mina[nt], __shfl_xor(mina[nt], 32));
    maxm[nt] = fmaxf(maxm[nt], __shfl_xor(maxm[nt], 16));
    maxm[nt] = fmaxf(maxm[nt], __shfl_xor(maxm[nt], 32));
    minm[nt] = fminf(minm[nt], __shfl_xor(minm[nt], 16));
    minm[nt] = fminf(minm[nt], __shfl_xor(minm[nt], 32));
  }
  if (active && g == 0) {
#pragma unroll
    for (int nt = 0; nt < 2; ++nt) {
      float4 sm = make_float4(maxm[nt], minm[nt], maxa[nt], mina[nt]);
      *(float4*)&sumg[(size_t)v * 128 + (nt * 16 + u) * 4] = sm;
    }
  }

  float contrib = 0.f;
  if (active) {
    contrib = (g == 0) ? sum[0] : (g == 1) ? sum[1] : (g == 2) ? ssq[0] : ssq[1];
  }
  s_red[wv][(g & 1) * 16 + u + (g >> 1) * 32] = contrib;
  __syncthreads();
  if (tid < 64) {
    float tot = s_red[0][tid] + s_red[1][tid] + s_red[2][tid] + s_red[3][tid];
    int copy = blockIdx.x & (NC2 - 1);
    int ch = tid & 31;
    int base = (tid < 32) ? WS_SUM2 : WS_SSQ2;
    atomicAdd(&ws[base + copy * U2 + ch], tot);
  }

  // ---- epilogue: zero-fill out4[fill_lo .. n4) ----
  long gtid = (long)blockIdx.x * 256 + tid;
  long gstride = (long)gridDim.x * 256;
  float4 zz = make_float4(0.f, 0.f, 0.f, 0.f);
  for (long i = fill_lo + gtid; i < n4; i += gstride) out4[i] = zz;
}

// ---------------------------------------------------------------------------
// Final pass: 8 voxels/block, thread = (voxel, channel). fin2 per thread,
// finalize from summaries, 2 coalesced atomicAdds.
// ---------------------------------------------------------------------------
__global__ __launch_bounds__(256) void k_final(
    const float* __restrict__ sumg, const float* __restrict__ cntg,
    const float* __restrict__ ws, const float* __restrict__ g2,
    const float* __restrict__ be2, const int* __restrict__ coord,
    float* __restrict__ out, int K, float invN) {
  int tid = threadIdx.x;
  int v = blockIdx.x * 8 + (tid >> 5);
  int ch = tid & 31;
  if (v >= K) return;

  float s = 0.f, q = 0.f;
#pragma unroll
  for (int c = 0; c < NC2; ++c) {
    s += ws[WS_SUM2 + c * U2 + ch];
    q += ws[WS_SSQ2 + c * U2 + ch];
  }
  float mean = s * invN;
  float var = q * invN - mean * mean;
  float A2 = g2[ch] / sqrtf(var + EPSV);
  float B2 = be2[ch] - mean * A2;

  float4 sm = *(const float4*)&sumg[(size_t)v * 128 + ch * 4];
  float cnt = cntg[v];

  float hm = (A2 >= 0.f) ? (A2 * sm.x + B2) : (A2 * sm.y + B2);
  float ag = (A2 >= 0.f) ? (A2 * sm.z + B2) : (A2 * sm.w + B2);
  float voxr = (cnt < 0.5f) ? 0.f : ((cnt > TT - 0.5f) ? hm : fmaxf(hm, 0.f));
  float voxa = (cnt < 0.5f) ? 0.f : ((cnt > TT - 0.5f) ? ag : fmaxf(ag, 0.f));

  const int4 cd = *(const int4*)&coord[4 * v];
  long base = ((((long)cd.x * DD + cd.y) * HD + cd.z) * WD + cd.w) * 64;
  atomicAdd(&out[base + ch], voxr);
  atomicAdd(&out[base + 32 + ch], voxa);
}

// ---------------------------------------------------------------------------
extern "C" void kernel_launch(void* const* d_in, const int* in_sizes, int n_in,
                              void* d_out, int out_size, void* d_ws,
                              size_t ws_size, hipStream_t stream) {
  const float* feat = (const float*)d_in[0];
  const float* w1 = (const float*)d_in[1];
  const float* b1 = (const float*)d_in[2];
  const float* g1 = (const float*)d_in[3];
  const float* be1 = (const float*)d_in[4];
  const float* w2 = (const float*)d_in[5];
  const float* b2 = (const float*)d_in[6];
  const float* g2 = (const float*)d_in[7];
  const float* be2 = (const float*)d_in[8];
  const int* coord = (const int*)d_in[9];
  float* out = (float*)d_out;
  float* ws = (float*)d_ws;

  int K = in_sizes[0] / (TT * CIN);
  int P = K * TT;
  float invN = 1.0f / (float)P;
  long n4 = (long)out_size / 4;
  long split4 = (n4 * 29) / 50;  // 58% of the fill in k_stats1

  float* sumg = ws + WS_SUM_OFF;
  float* cntg = sumg + (size_t)K * 128;

  (void)hipMemsetAsync(d_ws, 0, WS_ZERO_FLOATS * sizeof(float), stream);

  k_stats1<<<512, 256, 0, stream>>>(feat, w1, b1, ws, P, (float4*)out, split4);

  int vb = (K + 3) / 4;
  k_vfe2<<<vb, 256, 0, stream>>>(feat, w1, b1, g1, be1, w2, b2, ws, sumg, cntg,
                                 (float4*)out, split4, n4, K, invN);
  k_final<<<(K + 7) / 8, 256, 0, stream>>>(sumg, cntg, ws, g2, be2, coord, out,
                                           K, invN);
}

// Round 7
// 834.181 us; speedup vs baseline: 1.0355x; 1.0355x over previous
//
#include <hip/hip_runtime.h>
#include <math.h>

#define TT 35
#define DD 10
#define HD 400
#define WD 352
#define CIN 7
#define U1 16
#define U2 32
#define EPSV 1e-5f

// ws float layout
#define WS_SUM1 256   // 32 copies x 16
#define WS_SSQ1 768
#define WS_SUM2 1280  // 16 copies x 32
#define WS_SSQ2 1792
#define NC1 32
#define NC2 16
#define WS_ZERO_FLOATS 2304
#define WS_SUM_OFF 4096  // per-voxel channel summaries start here

typedef __bf16 bf16x8 __attribute__((ext_vector_type(8)));
typedef float f32x4 __attribute__((ext_vector_type(4)));

__device__ inline unsigned short f2bf(float x) {
  unsigned u = __builtin_bit_cast(unsigned, x);
  unsigned r = (u + 0x7fff + ((u >> 16) & 1)) >> 16;
  return (unsigned short)r;
}

// ---------------------------------------------------------------------------
// Layer-1 BN statistics (~12us, read-bound on 39MB).
// ---------------------------------------------------------------------------
__global__ __launch_bounds__(256) void k_stats1(
    const float* __restrict__ feat, const float* __restrict__ w1,
    const float* __restrict__ b1, float* __restrict__ ws, int P) {
  __shared__ float s_w1[CIN * U1];
  __shared__ float s_b1[U1];
  __shared__ float s_red[4][2 * U1];

  int tid = threadIdx.x;
  if (tid < CIN * U1) s_w1[tid] = w1[tid];
  if (tid < U1) s_b1[tid] = b1[tid];
  __syncthreads();

  float sum[U1], ssq[U1];
#pragma unroll
  for (int u = 0; u < U1; ++u) { sum[u] = 0.f; ssq[u] = 0.f; }

  int stride = gridDim.x * blockDim.x;
  for (int p = blockIdx.x * blockDim.x + tid; p < P; p += stride) {
    const float* f = feat + (size_t)p * CIN;
    float x[CIN];
#pragma unroll
    for (int c = 0; c < CIN; ++c) x[c] = f[c];
#pragma unroll
    for (int u = 0; u < U1; ++u) {
      float acc = s_b1[u];
#pragma unroll
      for (int c = 0; c < CIN; ++c) acc += x[c] * s_w1[c * U1 + u];
      float h = fmaxf(acc, 0.f);
      sum[u] += h;
      ssq[u] += h * h;
    }
  }

  int lane = tid & 63, wv = tid >> 6;
#pragma unroll
  for (int u = 0; u < U1; ++u) {
    float s = sum[u], q = ssq[u];
    for (int off = 32; off; off >>= 1) {
      s += __shfl_down(s, off);
      q += __shfl_down(q, off);
    }
    if (lane == 0) { s_red[wv][u] = s; s_red[wv][U1 + u] = q; }
  }
  __syncthreads();
  if (tid < 2 * U1) {
    float tot = s_red[0][tid] + s_red[1][tid] + s_red[2][tid] + s_red[3][tid];
    int copy = blockIdx.x & (NC1 - 1);
    int u = tid & (U1 - 1);
    int base = (tid < U1) ? WS_SUM1 : WS_SSQ1;
    atomicAdd(&ws[base + copy * U1 + u], tot);
  }
}

// ---------------------------------------------------------------------------
// Main pass: one wave per voxel, 4 voxels/block. Compute only (no fill).
//  - per-wave fin1; stage1 in registers; cat -> bf16 LDS; 6x MFMA
//  - per-(voxel,channel) summaries {maxm,minm,maxa,mina} (fp32) + cnt
//  - layer-2 stats partials -> ws atomics
// ---------------------------------------------------------------------------
__global__ __launch_bounds__(256) void k_vfe2(
    const float* __restrict__ feat, const float* __restrict__ w1,
    const float* __restrict__ b1, const float* __restrict__ g1,
    const float* __restrict__ be1, const float* __restrict__ w2,
    const float* __restrict__ b2, float* __restrict__ ws,
    float* __restrict__ sumg, float* __restrict__ cntg, int K, float invN) {
  __shared__ unsigned short s_w2b[32 * 40];     // [n][c'] stride 40
  __shared__ unsigned short s_catb[4][48][32];  // bf16 cat; pad rows 35-47 = 0
  __shared__ float s_mk[4][40];                 // mask per row
  __shared__ float s_red[4][64];

  int tid = threadIdx.x;
  int lane = tid & 63, wv = tid >> 6;
  int g = lane >> 4, u = lane & 15;
  int v = blockIdx.x * 4 + wv;
  bool active = (v < K);

  // ---- stage w2 -> bf16, transposed + K-permuted (c'=2i<->c=i, c'=2i+1<->c=16+i)
  for (int i = tid; i < 32 * 32; i += 256) {
    int n = i >> 5, cp = i & 31;
    int c = (cp & 1) ? (16 + (cp >> 1)) : (cp >> 1);
    s_w2b[n * 40 + cp] = f2bf(w2[c * 32 + n]);
  }
  // ---- zero M-pad rows 35..47 of each wave's cat tile ----
  {
    unsigned* z = (unsigned*)s_catb;
    for (int i = tid; i < 4 * 13 * 16; i += 256) {
      int w = i / 208, rem = i % 208;
      int row = 35 + (rem >> 4), k = rem & 15;
      z[(w * 48 + row) * 16 + k] = 0u;
    }
  }

  // ---- per-lane fin1: BN1 affine for channel u ----
  float s1 = 0.f, q1 = 0.f;
#pragma unroll
  for (int c = 0; c < NC1; ++c) {
    s1 += ws[WS_SUM1 + c * U1 + u];
    q1 += ws[WS_SSQ1 + c * U1 + u];
  }
  float mean1 = s1 * invN;
  float var1 = q1 * invN - mean1 * mean1;
  float A1 = g1[u] / sqrtf(var1 + EPSV);
  float B1 = be1[u] - mean1 * A1;

  float w1r[CIN];
#pragma unroll
  for (int c = 0; c < CIN; ++c) w1r[c] = w1[c * U1 + u];
  float b1u = b1[u];

  // ---- stage 1: rows t = g + 4j ----
  float h1n[9], mkv[9];
  float aggl = -INFINITY;
  float cntl = 0.f;
  const float* fv = feat + (size_t)v * (TT * CIN);
#pragma unroll
  for (int j = 0; j < 9; ++j) {
    int t = g + 4 * j;
    h1n[j] = -INFINITY;
    mkv[j] = 0.f;
    if (active && t < TT) {
      const float* fr = fv + t * CIN;
      float x0 = fr[0], x1 = fr[1], x2 = fr[2], x3 = fr[3];
      float x4 = fr[4], x5 = fr[5], x6 = fr[6];
      float m = fmaxf(fmaxf(fmaxf(x0, x1), fmaxf(x2, x3)),
                      fmaxf(fmaxf(x4, x5), x6));
      float mk = (m != 0.f) ? 1.f : 0.f;
      float acc = b1u + x0 * w1r[0] + x1 * w1r[1] + x2 * w1r[2] +
                  x3 * w1r[3] + x4 * w1r[4] + x5 * w1r[5] + x6 * w1r[6];
      float h = fmaxf(acc, 0.f);
      h1n[j] = A1 * h + B1;
      mkv[j] = mk;
      cntl += mk;
      if (u == 0) s_mk[wv][t] = mk;
      aggl = fmaxf(aggl, h1n[j]);
    }
  }
  // agg1 / cnt across the 4 g-groups (u-lanes within a group are identical)
  aggl = fmaxf(aggl, __shfl_xor(aggl, 16));
  aggl = fmaxf(aggl, __shfl_xor(aggl, 32));
  cntl += __shfl_xor(cntl, 16);
  cntl += __shfl_xor(cntl, 32);
  if (active && lane == 0) cntg[v] = cntl;

  // ---- write cat rows: packed (h*mk, agg*mk) bf16x2 at cols (2u, 2u+1) ----
#pragma unroll
  for (int j = 0; j < 9; ++j) {
    int t = g + 4 * j;
    if (active && t < TT) {
      unsigned pk = (unsigned)f2bf(h1n[j] * mkv[j]) |
                    ((unsigned)f2bf(aggl * mkv[j]) << 16);
      *(unsigned*)&s_catb[wv][t][2 * u] = pk;
    }
  }
  __syncthreads();

  // ---- stage 2: 6x MFMA ----
  f32x4 acc[2][3];
#pragma unroll
  for (int nt = 0; nt < 2; ++nt)
#pragma unroll
    for (int mt = 0; mt < 3; ++mt) acc[nt][mt] = (f32x4)(0.f);

  bf16x8 bfr[2];
#pragma unroll
  for (int nt = 0; nt < 2; ++nt) {
    uint4 raw = *(const uint4*)&s_w2b[(nt * 16 + u) * 40 + g * 8];
    bfr[nt] = __builtin_bit_cast(bf16x8, raw);
  }
#pragma unroll
  for (int mt = 0; mt < 3; ++mt) {
    uint4 raw = *(const uint4*)&s_catb[wv][mt * 16 + u][g * 8];
    bf16x8 afr = __builtin_bit_cast(bf16x8, raw);
#pragma unroll
    for (int nt = 0; nt < 2; ++nt)
      acc[nt][mt] =
          __builtin_amdgcn_mfma_f32_16x16x32_bf16(afr, bfr[nt], acc[nt][mt], 0, 0, 0);
  }

  // ---- bias+relu, layer-2 stats, channel summaries ----
  float b2c[2] = {b2[u], b2[16 + u]};
  float sum[2] = {0.f, 0.f}, ssq[2] = {0.f, 0.f};
  float maxm[2] = {-INFINITY, -INFINITY}, minm[2] = {INFINITY, INFINITY};
  float maxa[2] = {-INFINITY, -INFINITY}, mina[2] = {INFINITY, INFINITY};
#pragma unroll
  for (int nt = 0; nt < 2; ++nt) {
#pragma unroll
    for (int mt = 0; mt < 3; ++mt) {
#pragma unroll
      for (int r = 0; r < 4; ++r) {
        int row = mt * 16 + g * 4 + r;
        if (row < TT) {
          float h = fmaxf(acc[nt][mt][r] + b2c[nt], 0.f);
          sum[nt] += h;
          ssq[nt] += h * h;
          maxa[nt] = fmaxf(maxa[nt], h);
          mina[nt] = fminf(mina[nt], h);
          float mk = s_mk[wv][row];
          if (mk != 0.f) {
            maxm[nt] = fmaxf(maxm[nt], h);
            minm[nt] = fminf(minm[nt], h);
          }
        }
      }
    }
  }

  // reduce all summaries + stats across g-groups
#pragma unroll
  for (int nt = 0; nt < 2; ++nt) {
    sum[nt] += __shfl_xor(sum[nt], 16);
    sum[nt] += __shfl_xor(sum[nt], 32);
    ssq[nt] += __shfl_xor(ssq[nt], 16);
    ssq[nt] += __shfl_xor(ssq[nt], 32);
    maxa[nt] = fmaxf(maxa[nt], __shfl_xor(maxa[nt], 16));
    maxa[nt] = fmaxf(maxa[nt], __shfl_xor(maxa[nt], 32));
    mina[nt] = fminf(mina[nt], __shfl_xor(mina[nt], 16));
    mina[nt] = fminf(mina[nt], __shfl_xor(mina[nt], 32));
    maxm[nt] = fmaxf(maxm[nt], __shfl_xor(maxm[nt], 16));
    maxm[nt] = fmaxf(maxm[nt], __shfl_xor(maxm[nt], 32));
    minm[nt] = fminf(minm[nt], __shfl_xor(minm[nt], 16));
    minm[nt] = fminf(minm[nt], __shfl_xor(minm[nt], 32));
  }
  if (active && g == 0) {
#pragma unroll
    for (int nt = 0; nt < 2; ++nt) {
      float4 sm = make_float4(maxm[nt], minm[nt], maxa[nt], mina[nt]);
      *(float4*)&sumg[(size_t)v * 128 + (nt * 16 + u) * 4] = sm;
    }
  }

  float contrib = 0.f;
  if (active) {
    contrib = (g == 0) ? sum[0] : (g == 1) ? sum[1] : (g == 2) ? ssq[0] : ssq[1];
  }
  s_red[wv][(g & 1) * 16 + u + (g >> 1) * 32] = contrib;
  __syncthreads();
  if (tid < 64) {
    float tot = s_red[0][tid] + s_red[1][tid] + s_red[2][tid] + s_red[3][tid];
    int copy = blockIdx.x & (NC2 - 1);
    int ch = tid & 31;
    int base = (tid < 32) ? WS_SUM2 : WS_SSQ2;
    atomicAdd(&ws[base + copy * U2 + ch], tot);
  }
}

// ---------------------------------------------------------------------------
// Final pass: 8 voxels/block, thread = (voxel, channel). fin2 per thread,
// finalize from summaries, 2 coalesced atomicAdds.
// ---------------------------------------------------------------------------
__global__ __launch_bounds__(256) void k_final(
    const float* __restrict__ sumg, const float* __restrict__ cntg,
    const float* __restrict__ ws, const float* __restrict__ g2,
    const float* __restrict__ be2, const int* __restrict__ coord,
    float* __restrict__ out, int K, float invN) {
  int tid = threadIdx.x;
  int v = blockIdx.x * 8 + (tid >> 5);
  int ch = tid & 31;
  if (v >= K) return;

  float s = 0.f, q = 0.f;
#pragma unroll
  for (int c = 0; c < NC2; ++c) {
    s += ws[WS_SUM2 + c * U2 + ch];
    q += ws[WS_SSQ2 + c * U2 + ch];
  }
  float mean = s * invN;
  float var = q * invN - mean * mean;
  float A2 = g2[ch] / sqrtf(var + EPSV);
  float B2 = be2[ch] - mean * A2;

  float4 sm = *(const float4*)&sumg[(size_t)v * 128 + ch * 4];
  float cnt = cntg[v];

  float hm = (A2 >= 0.f) ? (A2 * sm.x + B2) : (A2 * sm.y + B2);
  float ag = (A2 >= 0.f) ? (A2 * sm.z + B2) : (A2 * sm.w + B2);
  float voxr = (cnt < 0.5f) ? 0.f : ((cnt > TT - 0.5f) ? hm : fmaxf(hm, 0.f));
  float voxa = (cnt < 0.5f) ? 0.f : ((cnt > TT - 0.5f) ? ag : fmaxf(ag, 0.f));

  const int4 cd = *(const int4*)&coord[4 * v];
  long base = ((((long)cd.x * DD + cd.y) * HD + cd.z) * WD + cd.w) * 64;
  atomicAdd(&out[base + ch], voxr);
  atomicAdd(&out[base + 32 + ch], voxa);
}

// ---------------------------------------------------------------------------
extern "C" void kernel_launch(void* const* d_in, const int* in_sizes, int n_in,
                              void* d_out, int out_size, void* d_ws,
                              size_t ws_size, hipStream_t stream) {
  const float* feat = (const float*)d_in[0];
  const float* w1 = (const float*)d_in[1];
  const float* b1 = (const float*)d_in[2];
  const float* g1 = (const float*)d_in[3];
  const float* be1 = (const float*)d_in[4];
  const float* w2 = (const float*)d_in[5];
  const float* b2 = (const float*)d_in[6];
  const float* g2 = (const float*)d_in[7];
  const float* be2 = (const float*)d_in[8];
  const int* coord = (const int*)d_in[9];
  float* out = (float*)d_out;
  float* ws = (float*)d_ws;

  int K = in_sizes[0] / (TT * CIN);
  int P = K * TT;
  float invN = 1.0f / (float)P;

  float* sumg = ws + WS_SUM_OFF;
  float* cntg = sumg + (size_t)K * 128;

  // Zero the 721MB output with the rocclr fill path (proven 6.4 TB/s) instead
  // of an in-kernel grid-stride fill (measured ~3.4 TB/s effective).
  (void)hipMemsetAsync(d_out, 0, (size_t)out_size * sizeof(float), stream);
  (void)hipMemsetAsync(d_ws, 0, WS_ZERO_FLOATS * sizeof(float), stream);

  k_stats1<<<512, 256, 0, stream>>>(feat, w1, b1, ws, P);

  int vb = (K + 3) / 4;
  k_vfe2<<<vb, 256, 0, stream>>>(feat, w1, b1, g1, be1, w2, b2, ws, sumg, cntg,
                                 K, invN);
  k_final<<<(K + 7) / 8, 256, 0, stream>>>(sumg, cntg, ws, g2, be2, coord, out,
                                           K, invN);
}